// Round 19
// baseline (182.270 us; speedup 1.0000x reference)
//
#include <hip/hip_runtime.h>
#include <stdint.h>

// Problem constants
#define AA 144          // ATOM*ATOM
#define LAM 0.1f

// ---- workspace layout (float offsets) ----
#define OFS_SC    0            // 64 scalars: [16]=scX*mu, [17]=scA, [18]=-scA*mu
#define OFS_AF1   64           // 128*144 row-normalized zero-mean atoms
#define OFS_G     36928        // 128*128 gram (f32)
#define OFS_S0    53312        // ATB (bf16 -mu*atoms_n, [128][160] u16, natural order)
#define OFS_S1    69696        // ANTBP (bf16 atoms_n^T, kslot-permuted cols, [144][128] u16)
#define OFS_X     86080        // XPB: bf16 mu*X, kslot-permuted cols, [128][128] u16
#define OFS_PM    139328       // 32768 patch means
#define OFS_GOAL  172096       // 45056 goal (f32)
#define OFS_CF    4411456      // cfgb: per 16-patch tile 64 lanes x 4 slots x u32x4
#define OFS_PRED  8605760      // predh: bf16 j-major [144][32768] u16
#define OFS_ATB   OFS_S0
#define OFS_ANTB  OFS_S1

// k-slot permutation (X / ANTBP / state B-frags):
//   ks = 32s + 8Q + j  <->  real n = 32s + 16(j>>2) + 4Q + (j&3)
// 4-wave split: wave w owns slot w (atoms 32w..32w+31, m-tiles 2w,2w+1).
// C/D accumulator (atom = 32w + 16m + 4Q + r) packs into slot w:
//   own[jj] = cvt_pk(pair jj of state).
// Round-2 lesson (rule #20): B-frag regs NAMED, never runtime-indexed.
// Rounds 10-11 lesson: the barrier-free LDS-X fista NaNs (bisected to
// k_fista; cause not identifiable by static inspection) — retired.
// Rounds 13-18: six consecutive clean runs, 181.9-182.7 us.
// FINAL banked configuration (session: 213.7 -> ~182 us, -15%).

typedef __attribute__((ext_vector_type(8))) short short8_t;
typedef __attribute__((ext_vector_type(4))) float f32x4;
typedef __attribute__((ext_vector_type(2))) float f32x2;
typedef __attribute__((ext_vector_type(4))) uint32_t u32x4;

__device__ __forceinline__ unsigned short f2bf(float f) {      // RNE
    union { float f; uint32_t u; } x; x.f = f;
    uint32_t u = x.u;
    return (unsigned short)((u + 0x7FFFu + ((u >> 16) & 1u)) >> 16);
}
__device__ __forceinline__ unsigned short f2bh(float f) {      // round-half-up (cheap)
    union { float f; uint32_t u; } x; x.f = f;
    return (unsigned short)((x.u + 0x8000u) >> 16);
}
__device__ __forceinline__ float bf2f(unsigned short u) {
    union { float f; uint32_t i; } x; x.i = ((uint32_t)u) << 16; return x.f;
}
// pack two f32 -> packed bf16 pair (a->low, b->high), round-half-up (VALU fallback)
__device__ __forceinline__ uint32_t pack_bf(float a, float b) {
    union { float f; uint32_t u; } xa, xb; xa.f = a; xb.f = b;
    return __builtin_amdgcn_perm(xb.u + 0x8000u, xa.u + 0x8000u, 0x07060302u);
}
// single-instruction pack (RNE)
__device__ __forceinline__ uint32_t cvt_pk(float a, float b) {
    uint32_t r;
    asm("v_cvt_pk_bf16_f32 %0, %1, %2" : "=v"(r) : "v"(a), "v"(b));
    return r;
}

// ---- setup: block 0 = norm + bf16 gram + 8x power squarings + Rayleigh (1024 thr);
//      blocks 1..45 = goal copy + patch means (run hidden under block 0's chain). ----
#define PSTR 136
__global__ __launch_bounds__(1024) void k_setup(const float* atoms, const float* mu_p,
                                                float* ws, const float* y) {
    __shared__ unsigned short ABf[128 * 168];       // 43008 B
    __shared__ unsigned short Pb[2][128 * PSTR];    // 69632 B
    __shared__ float tr_arr[10];
    __shared__ float v[128];
    __shared__ float red[256];
    int t = threadIdx.x;
    if (blockIdx.x != 0) {                          // worker blocks: goal + pm
        int e = (blockIdx.x - 1) * 1024 + t;        // < 46080
        if (e < 45000) ws[OFS_GOAL + e] = y[e];
        if (e < 32768) {
            int b = e >> 12, pi = (e >> 6) & 63, pj = e & 63;
            const float* yb = y + b * 5625;
            float s = 0.f;
            for (int di = 0; di < 12; ++di) {
                const float* row = yb + (pi + di) * 75 + pj;
                #pragma unroll
                for (int dj = 0; dj < 12; ++dj) s += row[dj];
            }
            ws[OFS_PM + e] = s * (1.0f / 144.0f);
        }
        return;
    }
    int lane = t & 63, w = t >> 6;
    int col = lane & 15, quad = lane >> 4;
    if (t < 10) tr_arr[t] = (t == 0) ? 128.0f : 0.f;

    // ---- norm: 8 threads/atom, width-8 shfl reductions ----
    {
        int a = t >> 3, sub = t & 7;
        const float* ap = atoms + a * AA + sub * 18;
        float s = 0.f;
        #pragma unroll
        for (int k = 0; k < 18; ++k) s += ap[k];
        s += __shfl_xor(s, 1, 8); s += __shfl_xor(s, 2, 8); s += __shfl_xor(s, 4, 8);
        float mean = s * (1.0f / 144.0f);
        float ss = 0.f;
        #pragma unroll
        for (int k = 0; k < 18; ++k) { float d = ap[k] - mean; ss = fmaf(d, d, ss); }
        ss += __shfl_xor(ss, 1, 8); ss += __shfl_xor(ss, 2, 8); ss += __shfl_xor(ss, 4, 8);
        float rn = 1.0f / sqrtf(ss);
        #pragma unroll
        for (int k = 0; k < 18; ++k) {
            float av = (ap[k] - mean) * rn;
            ws[OFS_AF1 + a * AA + sub * 18 + k] = av;
            ABf[a * 168 + sub * 18 + k] = f2bf(av);
        }
        if (sub == 0) {
            #pragma unroll
            for (int k = AA; k < 160; ++k) ABf[a * 168 + k] = 0;
        }
    }
    __syncthreads();

    // ---- gram: wave w -> m-tile (w&7), g-half (w>>3) ----
    {
        uint32_t* D32 = (uint32_t*)Pb[0];
        float* G = ws + OFS_G;
        int mt = w & 7, gh = w >> 3;
        short8_t af[5];
        #pragma unroll
        for (int s = 0; s < 5; ++s)
            af[s] = *(const short8_t*)&ABf[(mt * 16 + col) * 168 + s * 32 + quad * 8];
        #pragma unroll
        for (int gi = 0; gi < 2; ++gi) {
            int g = gh * 2 + gi;
            short8_t b0[5], b1[5];
            #pragma unroll
            for (int s = 0; s < 5; ++s) {
                b0[s] = *(const short8_t*)&ABf[((2 * g) * 16 + col) * 168 + s * 32 + quad * 8];
                b1[s] = *(const short8_t*)&ABf[((2 * g + 1) * 16 + col) * 168 + s * 32 + quad * 8];
            }
            f32x4 a0 = (f32x4){0.f, 0.f, 0.f, 0.f};
            f32x4 a1 = (f32x4){0.f, 0.f, 0.f, 0.f};
            #pragma unroll
            for (int s = 0; s < 5; ++s) {
                a0 = __builtin_amdgcn_mfma_f32_16x16x32_bf16(af[s], b0[s], a0, 0, 0, 0);
                a1 = __builtin_amdgcn_mfma_f32_16x16x32_bf16(af[s], b1[s], a1, 0, 0, 0);
            }
            #pragma unroll
            for (int r = 0; r < 4; ++r) {
                int m = mt * 16 + quad * 4 + r;
                G[m * 128 + g * 32 + col] = a0[r];
                G[m * 128 + g * 32 + 16 + col] = a1[r];
                D32[m * 68 + g * 16 + col] = pack_bf(a0[r], a1[r]);
            }
        }
    }
    __syncthreads();

    // ---- power: 8 squarings; wave w -> m-tile (w&7), n-quarter (w>>3) ----
    int cur = 0;
    #pragma unroll 1
    for (int j = 0; j < 8; ++j) {
        float trn = tr_arr[j];
        float inv2 = 1.0f / (trn * trn);
        const unsigned short* S = Pb[cur];
        uint32_t* D32 = (uint32_t*)Pb[cur ^ 1];
        int mt = w & 7, nh = w >> 3;
        short8_t af[4];
        #pragma unroll
        for (int s = 0; s < 4; ++s)
            af[s] = *(const short8_t*)&S[(mt * 16 + col) * PSTR + s * 32 + quad * 8];
        #pragma unroll
        for (int pr = 0; pr < 2; ++pr) {
            int ntE = 4 * nh + 2 * pr, ntO = ntE + 1;
            short8_t bE[4], bO[4];
            #pragma unroll
            for (int s = 0; s < 4; ++s) {
                bE[s] = *(const short8_t*)&S[(ntE * 16 + col) * PSTR + s * 32 + quad * 8];
                bO[s] = *(const short8_t*)&S[(ntO * 16 + col) * PSTR + s * 32 + quad * 8];
            }
            f32x4 aE = (f32x4){0.f, 0.f, 0.f, 0.f};
            f32x4 aO = (f32x4){0.f, 0.f, 0.f, 0.f};
            #pragma unroll
            for (int s = 0; s < 4; ++s) {
                aE = __builtin_amdgcn_mfma_f32_16x16x32_bf16(af[s], bE[s], aE, 0, 0, 0);
                aO = __builtin_amdgcn_mfma_f32_16x16x32_bf16(af[s], bO[s], aO, 0, 0, 0);
            }
            int nE = ntE * 16 + col, nO = ntO * 16 + col;
            #pragma unroll
            for (int r = 0; r < 4; ++r) {
                float x0 = aE[r] * inv2, x1 = aO[r] * inv2;
                int row = mt * 16 + quad * 4 + r;
                D32[row * 68 + (ntE >> 1) * 16 + col] = pack_bf(x0, x1);
                if (row == nE) atomicAdd(&tr_arr[j + 1], x0);
                if (row == nO) atomicAdd(&tr_arr[j + 1], x1);
            }
        }
        __syncthreads();
        cur ^= 1;
    }

    // ---- Rayleigh on f32 G (8 threads/row) ----
    {
        int a = t >> 3, sub = t & 7;
        const unsigned short* S = Pb[cur];
        float s = 0.f;
        #pragma unroll
        for (int k = 0; k < 16; ++k) s += bf2f(S[a * PSTR + sub * 16 + k]);
        s += __shfl_xor(s, 1, 8); s += __shfl_xor(s, 2, 8); s += __shfl_xor(s, 4, 8);
        if (sub == 0) v[a] = s;
    }
    __syncthreads();
    {
        int a = t >> 3, sub = t & 7;
        const float* G = ws + OFS_G;
        float wv = 0.f;
        #pragma unroll
        for (int k = 0; k < 16; ++k)
            wv = fmaf(G[a * 128 + sub * 16 + k], v[sub * 16 + k], wv);
        wv += __shfl_xor(wv, 1, 8); wv += __shfl_xor(wv, 2, 8); wv += __shfl_xor(wv, 4, 8);
        if (sub == 0) { red[a] = v[a] * wv; red[128 + a] = v[a] * v[a]; }
    }
    __syncthreads();
    for (int off = 64; off > 0; off >>= 1) {
        if (t < off) { red[t] += red[t + off]; red[128 + t] += red[128 + t + off]; }
        __syncthreads();
    }
    if (t == 0) {
        float lam = red[0] / red[128];
        float mu = fmaxf(mu_p[0], 0.0f);
        float scX = 1.0f / (lam * mu);
        float scA = 1.0f / (sqrtf(lam) * sqrtf(mu));
        ws[OFS_SC + 16] = scX * mu;     // X' = mu*X scale (= 1/lam)
        ws[OFS_SC + 17] = scA;          // atoms_n scale (pred path)
        ws[OFS_SC + 18] = -scA * mu;    // q path: -mu*atoms_n (negated, mu-folded)
    }
}

// ---- finalize: scale-dependent tables (XPB / ATB / ANTBP), kslot permutation ----
__global__ __launch_bounds__(256) void k_finalize(float* ws) {
    int idx = blockIdx.x * 256 + threadIdx.x;       // grid 216 -> 55296
    float scX = ws[OFS_SC + 16], scA = ws[OFS_SC + 17], scQ = ws[OFS_SC + 18];
    if (idx < 16384) {
        // XPB: rows natural (atom out), cols kslot-permuted; value = mu*X
        int row = idx >> 7, ks = idx & 127;
        int s = ks >> 5, Q = (ks >> 3) & 3, j = ks & 7;
        int n = 32 * s + 16 * (j >> 2) + 4 * Q + (j & 3);
        ((unsigned short*)(ws + OFS_X))[idx] = f2bf(ws[OFS_G + row * 128 + n] * scX);
    } else if (idx < 36864) {
        // ATB [n=128][k=160] zero-pad, natural orders; value = -mu*atoms_n
        int e = idx - 16384;
        int n = e / 160, k = e - n * 160;
        float v = (k < 144) ? ws[OFS_AF1 + n * 144 + k] * scQ : 0.f;
        ((unsigned short*)(ws + OFS_ATB))[e] = f2bf(v);
    } else {
        // ANTBP [j=144][ks=128] kslot-permuted cols; value = atoms_n
        int e = idx - 36864;
        int jr = e >> 7, ks = e & 127;
        int s = ks >> 5, Q = (ks >> 3) & 3, j = ks & 7;
        int n = 32 * s + 16 * (j >> 2) + 4 * Q + (j & 3);
        ((unsigned short*)(ws + OFS_ANTB))[e] = f2bf(ws[OFS_AF1 + n * 144 + jr] * scA);
    }
}

// ---- fused FISTA megakernel: 4 waves/block, TWO independent 16-patch tiles
//      (A,B) per block sharing X frags. Wave w owns slot w (32 atoms). Per
//      iteration: 16 MFMA (A then B, separate accs), two pair-state updates
//      with CONSTANT fm, ONE barrier covering both tiles' exchanges. ----
__global__ __launch_bounds__(256, 3) void k_fista(const unsigned short* XPB,
        const float* goal, const unsigned short* ATB, const unsigned short* ANTBP,
        const float* pm, uint32_t* cfgb, unsigned short* predh,
        int first, int write_cf) {
    __shared__ u32x4 Zx[2][2][4][64];           // [buf][tile][slot][lane], 16 KiB
    int t = threadIdx.x;
    int lane = t & 63, w = t >> 6;              // w = wave = owned k-slot
    int col = lane & 15, Q = lane >> 4;
    int sa = w ^ 1, sb = w ^ 2, sc = w ^ 3;     // other waves' slots
    int blk = blockIdx.x;                       // 1024 blocks: 32 patches each
    int b = blk >> 7, pi = (blk >> 1) & 63;
    int pcA = (blk & 1) * 32 + col;             // tile A pj ; tile B = +16
    int pA = blk * 32 + col, pB = pA + 16;      // global patch ids
    const float* gb = goal + b * 5625 + pi * 75;

    // ---- im2col B-frags for q, both tiles (max col = 47+10+17 = 74 < 75) ----
    u32x4 bqA[5], bqB[5];
    #pragma unroll
    for (int s = 0; s < 5; ++s)
        #pragma unroll
        for (int jj = 0; jj < 4; ++jj) {
            int k0 = 32 * s + 8 * Q + 2 * jj;   // even -> dj<=10, pair in-row
            float a0 = 0.f, a1 = 0.f, b0 = 0.f, b1 = 0.f;
            if (k0 < 144) {
                int di = k0 / 12, dj = k0 - di * 12;
                const float* r = gb + di * 75 + pcA + dj;
                a0 = r[0]; a1 = r[1];
                b0 = r[16]; b1 = r[17];
            }
            bqA[s][jj] = cvt_pk(a0, a1);
            bqB[s][jj] = cvt_pk(b0, b1);
        }

    // ---- qn = (-mu*atoms_n) @ patch, ATB frags shared across tiles ----
    f32x4 qnA[2], qnB[2];
    #pragma unroll
    for (int m = 0; m < 2; ++m) {
        f32x4 aA = (f32x4){0.f, 0.f, 0.f, 0.f};
        f32x4 aB = (f32x4){0.f, 0.f, 0.f, 0.f};
        #pragma unroll
        for (int s = 0; s < 5; ++s) {
            short8_t af = *(const short8_t*)&ATB[((w * 2 + m) * 16 + col) * 160 + 32 * s + 8 * Q];
            aA = __builtin_amdgcn_mfma_f32_16x16x32_bf16(af,
                     __builtin_bit_cast(short8_t, bqA[s]), aA, 0, 0, 0);
            aB = __builtin_amdgcn_mfma_f32_16x16x32_bf16(af,
                     __builtin_bit_cast(short8_t, bqB[s]), aB, 0, 0, 0);
        }
        qnA[m] = aA;
        qnB[m] = aB;
    }

    // ---- X' A-frags for the wave's 32 atom rows, all 4 k-slots (32 VGPR) ----
    short8_t xf_o[2], xf_a[2], xf_b[2], xf_c[2];
    #pragma unroll
    for (int m = 0; m < 2; ++m) {
        const unsigned short* Xr = &XPB[((w * 2 + m) * 16 + col) * 128 + 8 * Q];
        xf_o[m] = *(const short8_t*)&Xr[32 * w];
        xf_a[m] = *(const short8_t*)&Xr[32 * sa];
        xf_b[m] = *(const short8_t*)&Xr[32 * sb];
        xf_c[m] = *(const short8_t*)&Xr[32 * sc];
    }

    // ---- per-tile state as f32x2 pairs; named packed B-frag regs ----
    f32x2 zA[4], cPA[4], cQA[4], zB[4], cPB[4], cQB[4];
    f32x4 accA[2], accB[2];
    u32x4 ownA, othaA, othbA, othcA, ownB, othaB, othbB, othcB;
    if (first) {
        #pragma unroll
        for (int k = 0; k < 4; ++k) {
            zA[k] = cPA[k] = (f32x2){0.f, 0.f};
            zB[k] = cPB[k] = (f32x2){0.f, 0.f};
        }
        ownA = othaA = othbA = othcA = (u32x4){0u, 0u, 0u, 0u};
        ownB = othaB = othbB = othcB = (u32x4){0u, 0u, 0u, 0u};
    } else {
        const u32x4* cpA = (const u32x4*)(cfgb + ((size_t)(2 * blk) * 64 + lane) * 16);
        const u32x4* cpB = (const u32x4*)(cfgb + ((size_t)(2 * blk + 1) * 64 + lane) * 16);
        ownA = cpA[w]; othaA = cpA[sa]; othbA = cpA[sb]; othcA = cpA[sc];
        ownB = cpB[w]; othaB = cpB[sa]; othbB = cpB[sb]; othcB = cpB[sc];
        #pragma unroll
        for (int k = 0; k < 4; ++k) {           // unpack own slots -> pair state
            uint32_t a0 = ownA[k], b0 = ownB[k];
            cPA[k] = (f32x2){__builtin_bit_cast(float, a0 << 16),
                             __builtin_bit_cast(float, a0 & 0xFFFF0000u)};
            cPB[k] = (f32x2){__builtin_bit_cast(float, b0 << 16),
                             __builtin_bit_cast(float, b0 & 0xFFFF0000u)};
            zA[k] = cPA[k];
            zB[k] = cPB[k];
        }
    }

    // acc = z@X' - q'  (C-in of first k-step = qn = -mu*q; own slot first)
    auto matmul = [&](u32x4& o, u32x4& xa_, u32x4& xb_, u32x4& xc_,
                      f32x4 (&qn)[2], f32x4 (&acc)[2]) {
        #pragma unroll
        for (int m = 0; m < 2; ++m)
            acc[m] = __builtin_amdgcn_mfma_f32_16x16x32_bf16(xf_o[m],
                         __builtin_bit_cast(short8_t, o), qn[m], 0, 0, 0);
        #pragma unroll
        for (int m = 0; m < 2; ++m)
            acc[m] = __builtin_amdgcn_mfma_f32_16x16x32_bf16(xf_a[m],
                         __builtin_bit_cast(short8_t, xa_), acc[m], 0, 0, 0);
        #pragma unroll
        for (int m = 0; m < 2; ++m)
            acc[m] = __builtin_amdgcn_mfma_f32_16x16x32_bf16(xf_b[m],
                         __builtin_bit_cast(short8_t, xb_), acc[m], 0, 0, 0);
        #pragma unroll
        for (int m = 0; m < 2; ++m)
            acc[m] = __builtin_amdgcn_mfma_f32_16x16x32_bf16(xf_c[m],
                         __builtin_bit_cast(short8_t, xc_), acc[m], 0, 0, 0);
    };
    auto exchange = [&](int buf) {              // write own quarters, sync, read rest
        Zx[buf][0][w][lane] = ownA;
        Zx[buf][1][w][lane] = ownB;
        __syncthreads();
        othaA = Zx[buf][0][sa][lane];
        othbA = Zx[buf][0][sb][lane];
        othcA = Zx[buf][0][sc][lane];
        othaB = Zx[buf][1][sa][lane];
        othbB = Zx[buf][1][sb][lane];
        othcB = Zx[buf][1][sc][lane];
    };
    // z-iter update: cNew = prox(z - acc); z = cNew + fm*(cNew - cOld); pack z
    auto upd = [&](f32x2 (&z)[4], f32x2 (&cOld)[4], f32x2 (&cNew)[4],
                   f32x4 (&acc)[2], u32x4& o, float fm) {
        f32x2 fm2 = (f32x2){fm, fm};
        #pragma unroll
        for (int k = 0; k < 4; ++k) {
            f32x2 a2 = (f32x2){acc[k >> 1][2 * (k & 1)], acc[k >> 1][2 * (k & 1) + 1]};
            f32x2 u = z[k] - a2;                // z - mu*(z@X - q)
            f32x2 cl = (f32x2){__builtin_amdgcn_fmed3f(u[0], -LAM, LAM),
                               __builtin_amdgcn_fmed3f(u[1], -LAM, LAM)};
            f32x2 cn = u - cl;
            cNew[k] = cn;
            f32x2 zn = cn + fm2 * (cn - cOld[k]);
            z[k] = zn;
            o[k] = cvt_pk(zn[0], zn[1]);
        }
    };
    // prox-only: dst = prox(base - acc); pack dst
    auto prx = [&](f32x2 (&base)[4], f32x2 (&dst)[4], f32x4 (&acc)[2], u32x4& o) {
        #pragma unroll
        for (int k = 0; k < 4; ++k) {
            f32x2 a2 = (f32x2){acc[k >> 1][2 * (k & 1)], acc[k >> 1][2 * (k & 1) + 1]};
            f32x2 u = base[k] - a2;
            f32x2 cl = (f32x2){__builtin_amdgcn_fmed3f(u[0], -LAM, LAM),
                               __builtin_amdgcn_fmed3f(u[1], -LAM, LAM)};
            f32x2 cn = u - cl;
            dst[k] = cn;
            o[k] = cvt_pk(cn[0], cn[1]);
        }
    };

    // FISTA momentum schedule is input-independent: fm precomputed (f64->f32).
    #define ZITER(FM, CO, CN, BUF)                                         \
        do {                                                               \
            matmul(ownA, othaA, othbA, othcA, qnA, accA);                  \
            matmul(ownB, othaB, othbB, othcB, qnB, accB);                  \
            upd(zA, CO##A, CN##A, accA, ownA, FM);                         \
            upd(zB, CO##B, CN##B, accB, ownB, FM);                         \
            exchange(BUF);                                                 \
        } while (0)
    ZITER(0.00000000f, cP, cQ, 0);
    ZITER(0.28175333f, cQ, cP, 1);
    ZITER(0.43404370f, cP, cQ, 0);
    ZITER(0.53106374f, cQ, cP, 1);
    ZITER(0.59877861f, cP, cQ, 0);
    ZITER(0.64892339f, cQ, cP, 1);
    ZITER(0.68764594f, cP, cQ, 0);
    ZITER(0.71850003f, cQ, cP, 1);
    ZITER(0.74369097f, cP, cQ, 0);
    ZITER(0.76466381f, cQ, cP, 1);
    ZITER(0.78240892f, cP, cQ, 0);
    ZITER(0.79762527f, cQ, cP, 1);
    ZITER(0.81081957f, cP, cQ, 0);
    ZITER(0.82237667f, cQ, cP, 1);
    #undef ZITER
    {   // FISTA iter 15: c15 = prox(z - acc) only (z15 never consumed)
        matmul(ownA, othaA, othbA, othcA, qnA, accA);
        matmul(ownB, othaB, othbB, othcB, qnB, accB);
        prx(zA, cQA, accA, ownA);
        prx(zB, cQB, accB, ownB);
        exchange(0);
    }
    {   // final differentiable step: cf = prox(c15 - mu*(c15@X - q))
        matmul(ownA, othaA, othbA, othcA, qnA, accA);
        matmul(ownB, othaB, othbB, othcB, qnB, accB);
        prx(cQA, cQA, accA, ownA);
        prx(cQB, cQB, accB, ownB);
        exchange(1);
    }
    if (write_cf) {                             // persist full cf (own slot per wave)
        u32x4* cpA = (u32x4*)(cfgb + ((size_t)(2 * blk) * 64 + lane) * 16);
        u32x4* cpB = (u32x4*)(cfgb + ((size_t)(2 * blk + 1) * 64 + lane) * 16);
        cpA[w] = ownA;
        cpB[w] = ownB;
    }

    // ---- pred (j-major; jm 0-2|3-4|5-6|7-8 across waves, ANTBP shared) ----
    {
        float pmA = pm[pA], pmB = pm[pB];
        f32x4 pmA4 = (f32x4){pmA, pmA, pmA, pmA};
        f32x4 pmB4 = (f32x4){pmB, pmB, pmB, pmB};
        int jm0 = (w == 0) ? 0 : (2 * w + 1);
        int jmN = (w == 0) ? 3 : 2;
        #pragma unroll
        for (int ji = 0; ji < 3; ++ji) {
            if (ji < jmN) {
                int jm = jm0 + ji;
                const unsigned short* Ar = &ANTBP[(jm * 16 + col) * 128 + 8 * Q];
                short8_t an_o = *(const short8_t*)&Ar[32 * w];
                short8_t an_a = *(const short8_t*)&Ar[32 * sa];
                short8_t an_b = *(const short8_t*)&Ar[32 * sb];
                short8_t an_c = *(const short8_t*)&Ar[32 * sc];
                f32x4 a = pmA4;
                a = __builtin_amdgcn_mfma_f32_16x16x32_bf16(an_o,
                        __builtin_bit_cast(short8_t, ownA), a, 0, 0, 0);
                a = __builtin_amdgcn_mfma_f32_16x16x32_bf16(an_a,
                        __builtin_bit_cast(short8_t, othaA), a, 0, 0, 0);
                a = __builtin_amdgcn_mfma_f32_16x16x32_bf16(an_b,
                        __builtin_bit_cast(short8_t, othbA), a, 0, 0, 0);
                a = __builtin_amdgcn_mfma_f32_16x16x32_bf16(an_c,
                        __builtin_bit_cast(short8_t, othcA), a, 0, 0, 0);
                f32x4 bb = pmB4;
                bb = __builtin_amdgcn_mfma_f32_16x16x32_bf16(an_o,
                         __builtin_bit_cast(short8_t, ownB), bb, 0, 0, 0);
                bb = __builtin_amdgcn_mfma_f32_16x16x32_bf16(an_a,
                         __builtin_bit_cast(short8_t, othaB), bb, 0, 0, 0);
                bb = __builtin_amdgcn_mfma_f32_16x16x32_bf16(an_b,
                         __builtin_bit_cast(short8_t, othbB), bb, 0, 0, 0);
                bb = __builtin_amdgcn_mfma_f32_16x16x32_bf16(an_c,
                         __builtin_bit_cast(short8_t, othcB), bb, 0, 0, 0);
                #pragma unroll
                for (int r = 0; r < 4; ++r) {
                    predh[(jm * 16 + 4 * Q + r) * 32768 + pA] = f2bh(a[r]);
                    predh[(jm * 16 + 4 * Q + r) * 32768 + pB] = f2bh(bb[r]);
                }
            }
        }
    }
}

// ---- fold via LDS staging: block = (output row i, batch b); j-major bf16 pred. ----
__global__ __launch_bounds__(256) void k_fold(const float* y, const float* beta_p,
                                              const unsigned short* predh, float* goal,
                                              float* out, int write_out) {
    __shared__ float P[12 * 832];              // 39,936 B
    int i = blockIdx.x, b = blockIdx.y;
    int t = threadIdx.x;
    for (int di = 0; di < 12; ++di) {
        int pi = i - di;
        if ((unsigned)pi >= 64u) continue;     // uniform per block
        int base = (b << 12) + (pi << 6);
        #pragma unroll
        for (int it = 0; it < 3; ++it) {
            int e = t + it * 256;              // < 768 = 12 dj * 64 pj
            int dj = e >> 6, pj = e & 63;      // consecutive t -> consecutive pj
            P[di * 832 + pj * 13 + dj] = bf2f(predh[(di * 12 + dj) * 32768 + base + pj]);
        }
    }
    __syncthreads();
    if (t >= 75) return;
    int j = t;
    float S = 0.f;
    for (int di = 0; di < 12; ++di) {
        if ((unsigned)(i - di) >= 64u) continue;
        const float* Pd = &P[di * 832];
        #pragma unroll
        for (int dj = 0; dj < 12; ++dj) {
            int pj = j - dj;
            if ((unsigned)pj >= 64u) continue;
            S += Pd[pj * 13 + dj];
        }
    }
    int ci = min(i, 11) - max(i - 63, 0) + 1;
    int cj = min(j, 11) - max(j - 63, 0) + 1;
    float beta = fmaxf(beta_p[0], 0.0f);
    int idx = i * 75 + j;
    float yv = y[b * 5625 + idx];
    float g = (yv + beta * S) / (1.0f + beta * (float)(ci * cj));
    if (write_out) out[b * 5625 + idx] = g;
    else           goal[b * 5625 + idx] = g;
}

extern "C" void kernel_launch(void* const* d_in, const int* in_sizes, int n_in,
                              void* d_out, int out_size, void* d_ws, size_t ws_size,
                              hipStream_t stream) {
    const float* y     = (const float*)d_in[0];
    const float* atoms = (const float*)d_in[1];
    const float* beta  = (const float*)d_in[2];
    const float* mu    = (const float*)d_in[3];
    float* out = (float*)d_out;
    float* ws = (float*)d_ws;

    k_setup<<<46, 1024, 0, stream>>>(atoms, mu, ws, y);   // block0 chain + workers goal/pm
    k_finalize<<<216, 256, 0, stream>>>(ws);              // XPB + ATB + ANTBP

    for (int u = 0; u < 2; ++u) {
        k_fista<<<1024, 256, 0, stream>>>((const unsigned short*)(ws + OFS_X),
                                          ws + OFS_GOAL,
                                          (const unsigned short*)(ws + OFS_ATB),
                                          (const unsigned short*)(ws + OFS_ANTB),
                                          ws + OFS_PM, (uint32_t*)(ws + OFS_CF),
                                          (unsigned short*)(ws + OFS_PRED),
                                          u == 0 ? 1 : 0, u == 0 ? 1 : 0);
        k_fold<<<dim3(75, 8), 256, 0, stream>>>(y, beta,
                                                (const unsigned short*)(ws + OFS_PRED),
                                                ws + OFS_GOAL, out, u == 1 ? 1 : 0);
    }
}

// Round 20
// 181.687 us; speedup vs baseline: 1.0032x; 1.0032x over previous
//
#include <hip/hip_runtime.h>
#include <stdint.h>

// Problem constants
#define AA 144          // ATOM*ATOM
#define LAM 0.1f

// ---- workspace layout (float offsets) ----
#define OFS_SC    0            // 64 scalars: [16]=scX*mu, [17]=scA, [18]=-scA*mu
#define OFS_AF1   64           // 128*144 row-normalized zero-mean atoms
#define OFS_G     36928        // 128*128 gram (f32)
#define OFS_S0    53312        // ATB (bf16 -mu*atoms_n, [128][160] u16, natural order)
#define OFS_S1    69696        // ANTBP (bf16 atoms_n^T, kslot-permuted cols, [144][128] u16)
#define OFS_X     86080        // XPB: bf16 mu*X, kslot-permuted cols, [128][128] u16
#define OFS_PM    139328       // 32768 patch means
#define OFS_GOAL  172096       // 45056 goal (f32)
#define OFS_CF    4411456      // cfgb: per 16-patch tile 64 lanes x 4 slots x u32x4
#define OFS_PRED  8605760      // predh: bf16 j-major [144][32768] u16
#define OFS_ATB   OFS_S0
#define OFS_ANTB  OFS_S1

// k-slot permutation (X / ANTBP / state B-frags):
//   ks = 32s + 8Q + j  <->  real n = 32s + 16(j>>2) + 4Q + (j&3)
// 4-wave split: wave w owns slot w (atoms 32w..32w+31, m-tiles 2w,2w+1).
// C/D accumulator (atom = 32w + 16m + 4Q + r) packs into slot w:
//   own[jj] = cvt_pk(pair jj of state).
// Round-2 lesson (rule #20): B-frag regs NAMED, never runtime-indexed.
// Rounds 10-11 lesson: the barrier-free LDS-X fista NaNs (bisected to
// k_fista; cause not identifiable by static inspection) — retired.
// Rounds 13-19: seven consecutive clean runs, 181.9-182.7 us.
// FINAL banked configuration (session: 213.7 -> ~182 us, -15%).

typedef __attribute__((ext_vector_type(8))) short short8_t;
typedef __attribute__((ext_vector_type(4))) float f32x4;
typedef __attribute__((ext_vector_type(2))) float f32x2;
typedef __attribute__((ext_vector_type(4))) uint32_t u32x4;

__device__ __forceinline__ unsigned short f2bf(float f) {      // RNE
    union { float f; uint32_t u; } x; x.f = f;
    uint32_t u = x.u;
    return (unsigned short)((u + 0x7FFFu + ((u >> 16) & 1u)) >> 16);
}
__device__ __forceinline__ unsigned short f2bh(float f) {      // round-half-up (cheap)
    union { float f; uint32_t u; } x; x.f = f;
    return (unsigned short)((x.u + 0x8000u) >> 16);
}
__device__ __forceinline__ float bf2f(unsigned short u) {
    union { float f; uint32_t i; } x; x.i = ((uint32_t)u) << 16; return x.f;
}
// pack two f32 -> packed bf16 pair (a->low, b->high), round-half-up (VALU fallback)
__device__ __forceinline__ uint32_t pack_bf(float a, float b) {
    union { float f; uint32_t u; } xa, xb; xa.f = a; xb.f = b;
    return __builtin_amdgcn_perm(xb.u + 0x8000u, xa.u + 0x8000u, 0x07060302u);
}
// single-instruction pack (RNE)
__device__ __forceinline__ uint32_t cvt_pk(float a, float b) {
    uint32_t r;
    asm("v_cvt_pk_bf16_f32 %0, %1, %2" : "=v"(r) : "v"(a), "v"(b));
    return r;
}

// ---- setup: block 0 = norm + bf16 gram + 8x power squarings + Rayleigh (1024 thr);
//      blocks 1..45 = goal copy + patch means (run hidden under block 0's chain). ----
#define PSTR 136
__global__ __launch_bounds__(1024) void k_setup(const float* atoms, const float* mu_p,
                                                float* ws, const float* y) {
    __shared__ unsigned short ABf[128 * 168];       // 43008 B
    __shared__ unsigned short Pb[2][128 * PSTR];    // 69632 B
    __shared__ float tr_arr[10];
    __shared__ float v[128];
    __shared__ float red[256];
    int t = threadIdx.x;
    if (blockIdx.x != 0) {                          // worker blocks: goal + pm
        int e = (blockIdx.x - 1) * 1024 + t;        // < 46080
        if (e < 45000) ws[OFS_GOAL + e] = y[e];
        if (e < 32768) {
            int b = e >> 12, pi = (e >> 6) & 63, pj = e & 63;
            const float* yb = y + b * 5625;
            float s = 0.f;
            for (int di = 0; di < 12; ++di) {
                const float* row = yb + (pi + di) * 75 + pj;
                #pragma unroll
                for (int dj = 0; dj < 12; ++dj) s += row[dj];
            }
            ws[OFS_PM + e] = s * (1.0f / 144.0f);
        }
        return;
    }
    int lane = t & 63, w = t >> 6;
    int col = lane & 15, quad = lane >> 4;
    if (t < 10) tr_arr[t] = (t == 0) ? 128.0f : 0.f;

    // ---- norm: 8 threads/atom, width-8 shfl reductions ----
    {
        int a = t >> 3, sub = t & 7;
        const float* ap = atoms + a * AA + sub * 18;
        float s = 0.f;
        #pragma unroll
        for (int k = 0; k < 18; ++k) s += ap[k];
        s += __shfl_xor(s, 1, 8); s += __shfl_xor(s, 2, 8); s += __shfl_xor(s, 4, 8);
        float mean = s * (1.0f / 144.0f);
        float ss = 0.f;
        #pragma unroll
        for (int k = 0; k < 18; ++k) { float d = ap[k] - mean; ss = fmaf(d, d, ss); }
        ss += __shfl_xor(ss, 1, 8); ss += __shfl_xor(ss, 2, 8); ss += __shfl_xor(ss, 4, 8);
        float rn = 1.0f / sqrtf(ss);
        #pragma unroll
        for (int k = 0; k < 18; ++k) {
            float av = (ap[k] - mean) * rn;
            ws[OFS_AF1 + a * AA + sub * 18 + k] = av;
            ABf[a * 168 + sub * 18 + k] = f2bf(av);
        }
        if (sub == 0) {
            #pragma unroll
            for (int k = AA; k < 160; ++k) ABf[a * 168 + k] = 0;
        }
    }
    __syncthreads();

    // ---- gram: wave w -> m-tile (w&7), g-half (w>>3) ----
    {
        uint32_t* D32 = (uint32_t*)Pb[0];
        float* G = ws + OFS_G;
        int mt = w & 7, gh = w >> 3;
        short8_t af[5];
        #pragma unroll
        for (int s = 0; s < 5; ++s)
            af[s] = *(const short8_t*)&ABf[(mt * 16 + col) * 168 + s * 32 + quad * 8];
        #pragma unroll
        for (int gi = 0; gi < 2; ++gi) {
            int g = gh * 2 + gi;
            short8_t b0[5], b1[5];
            #pragma unroll
            for (int s = 0; s < 5; ++s) {
                b0[s] = *(const short8_t*)&ABf[((2 * g) * 16 + col) * 168 + s * 32 + quad * 8];
                b1[s] = *(const short8_t*)&ABf[((2 * g + 1) * 16 + col) * 168 + s * 32 + quad * 8];
            }
            f32x4 a0 = (f32x4){0.f, 0.f, 0.f, 0.f};
            f32x4 a1 = (f32x4){0.f, 0.f, 0.f, 0.f};
            #pragma unroll
            for (int s = 0; s < 5; ++s) {
                a0 = __builtin_amdgcn_mfma_f32_16x16x32_bf16(af[s], b0[s], a0, 0, 0, 0);
                a1 = __builtin_amdgcn_mfma_f32_16x16x32_bf16(af[s], b1[s], a1, 0, 0, 0);
            }
            #pragma unroll
            for (int r = 0; r < 4; ++r) {
                int m = mt * 16 + quad * 4 + r;
                G[m * 128 + g * 32 + col] = a0[r];
                G[m * 128 + g * 32 + 16 + col] = a1[r];
                D32[m * 68 + g * 16 + col] = pack_bf(a0[r], a1[r]);
            }
        }
    }
    __syncthreads();

    // ---- power: 8 squarings; wave w -> m-tile (w&7), n-quarter (w>>3) ----
    int cur = 0;
    #pragma unroll 1
    for (int j = 0; j < 8; ++j) {
        float trn = tr_arr[j];
        float inv2 = 1.0f / (trn * trn);
        const unsigned short* S = Pb[cur];
        uint32_t* D32 = (uint32_t*)Pb[cur ^ 1];
        int mt = w & 7, nh = w >> 3;
        short8_t af[4];
        #pragma unroll
        for (int s = 0; s < 4; ++s)
            af[s] = *(const short8_t*)&S[(mt * 16 + col) * PSTR + s * 32 + quad * 8];
        #pragma unroll
        for (int pr = 0; pr < 2; ++pr) {
            int ntE = 4 * nh + 2 * pr, ntO = ntE + 1;
            short8_t bE[4], bO[4];
            #pragma unroll
            for (int s = 0; s < 4; ++s) {
                bE[s] = *(const short8_t*)&S[(ntE * 16 + col) * PSTR + s * 32 + quad * 8];
                bO[s] = *(const short8_t*)&S[(ntO * 16 + col) * PSTR + s * 32 + quad * 8];
            }
            f32x4 aE = (f32x4){0.f, 0.f, 0.f, 0.f};
            f32x4 aO = (f32x4){0.f, 0.f, 0.f, 0.f};
            #pragma unroll
            for (int s = 0; s < 4; ++s) {
                aE = __builtin_amdgcn_mfma_f32_16x16x32_bf16(af[s], bE[s], aE, 0, 0, 0);
                aO = __builtin_amdgcn_mfma_f32_16x16x32_bf16(af[s], bO[s], aO, 0, 0, 0);
            }
            int nE = ntE * 16 + col, nO = ntO * 16 + col;
            #pragma unroll
            for (int r = 0; r < 4; ++r) {
                float x0 = aE[r] * inv2, x1 = aO[r] * inv2;
                int row = mt * 16 + quad * 4 + r;
                D32[row * 68 + (ntE >> 1) * 16 + col] = pack_bf(x0, x1);
                if (row == nE) atomicAdd(&tr_arr[j + 1], x0);
                if (row == nO) atomicAdd(&tr_arr[j + 1], x1);
            }
        }
        __syncthreads();
        cur ^= 1;
    }

    // ---- Rayleigh on f32 G (8 threads/row) ----
    {
        int a = t >> 3, sub = t & 7;
        const unsigned short* S = Pb[cur];
        float s = 0.f;
        #pragma unroll
        for (int k = 0; k < 16; ++k) s += bf2f(S[a * PSTR + sub * 16 + k]);
        s += __shfl_xor(s, 1, 8); s += __shfl_xor(s, 2, 8); s += __shfl_xor(s, 4, 8);
        if (sub == 0) v[a] = s;
    }
    __syncthreads();
    {
        int a = t >> 3, sub = t & 7;
        const float* G = ws + OFS_G;
        float wv = 0.f;
        #pragma unroll
        for (int k = 0; k < 16; ++k)
            wv = fmaf(G[a * 128 + sub * 16 + k], v[sub * 16 + k], wv);
        wv += __shfl_xor(wv, 1, 8); wv += __shfl_xor(wv, 2, 8); wv += __shfl_xor(wv, 4, 8);
        if (sub == 0) { red[a] = v[a] * wv; red[128 + a] = v[a] * v[a]; }
    }
    __syncthreads();
    for (int off = 64; off > 0; off >>= 1) {
        if (t < off) { red[t] += red[t + off]; red[128 + t] += red[128 + t + off]; }
        __syncthreads();
    }
    if (t == 0) {
        float lam = red[0] / red[128];
        float mu = fmaxf(mu_p[0], 0.0f);
        float scX = 1.0f / (lam * mu);
        float scA = 1.0f / (sqrtf(lam) * sqrtf(mu));
        ws[OFS_SC + 16] = scX * mu;     // X' = mu*X scale (= 1/lam)
        ws[OFS_SC + 17] = scA;          // atoms_n scale (pred path)
        ws[OFS_SC + 18] = -scA * mu;    // q path: -mu*atoms_n (negated, mu-folded)
    }
}

// ---- finalize: scale-dependent tables (XPB / ATB / ANTBP), kslot permutation ----
__global__ __launch_bounds__(256) void k_finalize(float* ws) {
    int idx = blockIdx.x * 256 + threadIdx.x;       // grid 216 -> 55296
    float scX = ws[OFS_SC + 16], scA = ws[OFS_SC + 17], scQ = ws[OFS_SC + 18];
    if (idx < 16384) {
        // XPB: rows natural (atom out), cols kslot-permuted; value = mu*X
        int row = idx >> 7, ks = idx & 127;
        int s = ks >> 5, Q = (ks >> 3) & 3, j = ks & 7;
        int n = 32 * s + 16 * (j >> 2) + 4 * Q + (j & 3);
        ((unsigned short*)(ws + OFS_X))[idx] = f2bf(ws[OFS_G + row * 128 + n] * scX);
    } else if (idx < 36864) {
        // ATB [n=128][k=160] zero-pad, natural orders; value = -mu*atoms_n
        int e = idx - 16384;
        int n = e / 160, k = e - n * 160;
        float v = (k < 144) ? ws[OFS_AF1 + n * 144 + k] * scQ : 0.f;
        ((unsigned short*)(ws + OFS_ATB))[e] = f2bf(v);
    } else {
        // ANTBP [j=144][ks=128] kslot-permuted cols; value = atoms_n
        int e = idx - 36864;
        int jr = e >> 7, ks = e & 127;
        int s = ks >> 5, Q = (ks >> 3) & 3, j = ks & 7;
        int n = 32 * s + 16 * (j >> 2) + 4 * Q + (j & 3);
        ((unsigned short*)(ws + OFS_ANTB))[e] = f2bf(ws[OFS_AF1 + n * 144 + jr] * scA);
    }
}

// ---- fused FISTA megakernel: 4 waves/block, TWO independent 16-patch tiles
//      (A,B) per block sharing X frags. Wave w owns slot w (32 atoms). Per
//      iteration: 16 MFMA (A then B, separate accs), two pair-state updates
//      with CONSTANT fm, ONE barrier covering both tiles' exchanges. ----
__global__ __launch_bounds__(256, 3) void k_fista(const unsigned short* XPB,
        const float* goal, const unsigned short* ATB, const unsigned short* ANTBP,
        const float* pm, uint32_t* cfgb, unsigned short* predh,
        int first, int write_cf) {
    __shared__ u32x4 Zx[2][2][4][64];           // [buf][tile][slot][lane], 16 KiB
    int t = threadIdx.x;
    int lane = t & 63, w = t >> 6;              // w = wave = owned k-slot
    int col = lane & 15, Q = lane >> 4;
    int sa = w ^ 1, sb = w ^ 2, sc = w ^ 3;     // other waves' slots
    int blk = blockIdx.x;                       // 1024 blocks: 32 patches each
    int b = blk >> 7, pi = (blk >> 1) & 63;
    int pcA = (blk & 1) * 32 + col;             // tile A pj ; tile B = +16
    int pA = blk * 32 + col, pB = pA + 16;      // global patch ids
    const float* gb = goal + b * 5625 + pi * 75;

    // ---- im2col B-frags for q, both tiles (max col = 47+10+17 = 74 < 75) ----
    u32x4 bqA[5], bqB[5];
    #pragma unroll
    for (int s = 0; s < 5; ++s)
        #pragma unroll
        for (int jj = 0; jj < 4; ++jj) {
            int k0 = 32 * s + 8 * Q + 2 * jj;   // even -> dj<=10, pair in-row
            float a0 = 0.f, a1 = 0.f, b0 = 0.f, b1 = 0.f;
            if (k0 < 144) {
                int di = k0 / 12, dj = k0 - di * 12;
                const float* r = gb + di * 75 + pcA + dj;
                a0 = r[0]; a1 = r[1];
                b0 = r[16]; b1 = r[17];
            }
            bqA[s][jj] = cvt_pk(a0, a1);
            bqB[s][jj] = cvt_pk(b0, b1);
        }

    // ---- qn = (-mu*atoms_n) @ patch, ATB frags shared across tiles ----
    f32x4 qnA[2], qnB[2];
    #pragma unroll
    for (int m = 0; m < 2; ++m) {
        f32x4 aA = (f32x4){0.f, 0.f, 0.f, 0.f};
        f32x4 aB = (f32x4){0.f, 0.f, 0.f, 0.f};
        #pragma unroll
        for (int s = 0; s < 5; ++s) {
            short8_t af = *(const short8_t*)&ATB[((w * 2 + m) * 16 + col) * 160 + 32 * s + 8 * Q];
            aA = __builtin_amdgcn_mfma_f32_16x16x32_bf16(af,
                     __builtin_bit_cast(short8_t, bqA[s]), aA, 0, 0, 0);
            aB = __builtin_amdgcn_mfma_f32_16x16x32_bf16(af,
                     __builtin_bit_cast(short8_t, bqB[s]), aB, 0, 0, 0);
        }
        qnA[m] = aA;
        qnB[m] = aB;
    }

    // ---- X' A-frags for the wave's 32 atom rows, all 4 k-slots (32 VGPR) ----
    short8_t xf_o[2], xf_a[2], xf_b[2], xf_c[2];
    #pragma unroll
    for (int m = 0; m < 2; ++m) {
        const unsigned short* Xr = &XPB[((w * 2 + m) * 16 + col) * 128 + 8 * Q];
        xf_o[m] = *(const short8_t*)&Xr[32 * w];
        xf_a[m] = *(const short8_t*)&Xr[32 * sa];
        xf_b[m] = *(const short8_t*)&Xr[32 * sb];
        xf_c[m] = *(const short8_t*)&Xr[32 * sc];
    }

    // ---- per-tile state as f32x2 pairs; named packed B-frag regs ----
    f32x2 zA[4], cPA[4], cQA[4], zB[4], cPB[4], cQB[4];
    f32x4 accA[2], accB[2];
    u32x4 ownA, othaA, othbA, othcA, ownB, othaB, othbB, othcB;
    if (first) {
        #pragma unroll
        for (int k = 0; k < 4; ++k) {
            zA[k] = cPA[k] = (f32x2){0.f, 0.f};
            zB[k] = cPB[k] = (f32x2){0.f, 0.f};
        }
        ownA = othaA = othbA = othcA = (u32x4){0u, 0u, 0u, 0u};
        ownB = othaB = othbB = othcB = (u32x4){0u, 0u, 0u, 0u};
    } else {
        const u32x4* cpA = (const u32x4*)(cfgb + ((size_t)(2 * blk) * 64 + lane) * 16);
        const u32x4* cpB = (const u32x4*)(cfgb + ((size_t)(2 * blk + 1) * 64 + lane) * 16);
        ownA = cpA[w]; othaA = cpA[sa]; othbA = cpA[sb]; othcA = cpA[sc];
        ownB = cpB[w]; othaB = cpB[sa]; othbB = cpB[sb]; othcB = cpB[sc];
        #pragma unroll
        for (int k = 0; k < 4; ++k) {           // unpack own slots -> pair state
            uint32_t a0 = ownA[k], b0 = ownB[k];
            cPA[k] = (f32x2){__builtin_bit_cast(float, a0 << 16),
                             __builtin_bit_cast(float, a0 & 0xFFFF0000u)};
            cPB[k] = (f32x2){__builtin_bit_cast(float, b0 << 16),
                             __builtin_bit_cast(float, b0 & 0xFFFF0000u)};
            zA[k] = cPA[k];
            zB[k] = cPB[k];
        }
    }

    // acc = z@X' - q'  (C-in of first k-step = qn = -mu*q; own slot first)
    auto matmul = [&](u32x4& o, u32x4& xa_, u32x4& xb_, u32x4& xc_,
                      f32x4 (&qn)[2], f32x4 (&acc)[2]) {
        #pragma unroll
        for (int m = 0; m < 2; ++m)
            acc[m] = __builtin_amdgcn_mfma_f32_16x16x32_bf16(xf_o[m],
                         __builtin_bit_cast(short8_t, o), qn[m], 0, 0, 0);
        #pragma unroll
        for (int m = 0; m < 2; ++m)
            acc[m] = __builtin_amdgcn_mfma_f32_16x16x32_bf16(xf_a[m],
                         __builtin_bit_cast(short8_t, xa_), acc[m], 0, 0, 0);
        #pragma unroll
        for (int m = 0; m < 2; ++m)
            acc[m] = __builtin_amdgcn_mfma_f32_16x16x32_bf16(xf_b[m],
                         __builtin_bit_cast(short8_t, xb_), acc[m], 0, 0, 0);
        #pragma unroll
        for (int m = 0; m < 2; ++m)
            acc[m] = __builtin_amdgcn_mfma_f32_16x16x32_bf16(xf_c[m],
                         __builtin_bit_cast(short8_t, xc_), acc[m], 0, 0, 0);
    };
    auto exchange = [&](int buf) {              // write own quarters, sync, read rest
        Zx[buf][0][w][lane] = ownA;
        Zx[buf][1][w][lane] = ownB;
        __syncthreads();
        othaA = Zx[buf][0][sa][lane];
        othbA = Zx[buf][0][sb][lane];
        othcA = Zx[buf][0][sc][lane];
        othaB = Zx[buf][1][sa][lane];
        othbB = Zx[buf][1][sb][lane];
        othcB = Zx[buf][1][sc][lane];
    };
    // z-iter update: cNew = prox(z - acc); z = cNew + fm*(cNew - cOld); pack z
    auto upd = [&](f32x2 (&z)[4], f32x2 (&cOld)[4], f32x2 (&cNew)[4],
                   f32x4 (&acc)[2], u32x4& o, float fm) {
        f32x2 fm2 = (f32x2){fm, fm};
        #pragma unroll
        for (int k = 0; k < 4; ++k) {
            f32x2 a2 = (f32x2){acc[k >> 1][2 * (k & 1)], acc[k >> 1][2 * (k & 1) + 1]};
            f32x2 u = z[k] - a2;                // z - mu*(z@X - q)
            f32x2 cl = (f32x2){__builtin_amdgcn_fmed3f(u[0], -LAM, LAM),
                               __builtin_amdgcn_fmed3f(u[1], -LAM, LAM)};
            f32x2 cn = u - cl;
            cNew[k] = cn;
            f32x2 zn = cn + fm2 * (cn - cOld[k]);
            z[k] = zn;
            o[k] = cvt_pk(zn[0], zn[1]);
        }
    };
    // prox-only: dst = prox(base - acc); pack dst
    auto prx = [&](f32x2 (&base)[4], f32x2 (&dst)[4], f32x4 (&acc)[2], u32x4& o) {
        #pragma unroll
        for (int k = 0; k < 4; ++k) {
            f32x2 a2 = (f32x2){acc[k >> 1][2 * (k & 1)], acc[k >> 1][2 * (k & 1) + 1]};
            f32x2 u = base[k] - a2;
            f32x2 cl = (f32x2){__builtin_amdgcn_fmed3f(u[0], -LAM, LAM),
                               __builtin_amdgcn_fmed3f(u[1], -LAM, LAM)};
            f32x2 cn = u - cl;
            dst[k] = cn;
            o[k] = cvt_pk(cn[0], cn[1]);
        }
    };

    // FISTA momentum schedule is input-independent: fm precomputed (f64->f32).
    #define ZITER(FM, CO, CN, BUF)                                         \
        do {                                                               \
            matmul(ownA, othaA, othbA, othcA, qnA, accA);                  \
            matmul(ownB, othaB, othbB, othcB, qnB, accB);                  \
            upd(zA, CO##A, CN##A, accA, ownA, FM);                         \
            upd(zB, CO##B, CN##B, accB, ownB, FM);                         \
            exchange(BUF);                                                 \
        } while (0)
    ZITER(0.00000000f, cP, cQ, 0);
    ZITER(0.28175333f, cQ, cP, 1);
    ZITER(0.43404370f, cP, cQ, 0);
    ZITER(0.53106374f, cQ, cP, 1);
    ZITER(0.59877861f, cP, cQ, 0);
    ZITER(0.64892339f, cQ, cP, 1);
    ZITER(0.68764594f, cP, cQ, 0);
    ZITER(0.71850003f, cQ, cP, 1);
    ZITER(0.74369097f, cP, cQ, 0);
    ZITER(0.76466381f, cQ, cP, 1);
    ZITER(0.78240892f, cP, cQ, 0);
    ZITER(0.79762527f, cQ, cP, 1);
    ZITER(0.81081957f, cP, cQ, 0);
    ZITER(0.82237667f, cQ, cP, 1);
    #undef ZITER
    {   // FISTA iter 15: c15 = prox(z - acc) only (z15 never consumed)
        matmul(ownA, othaA, othbA, othcA, qnA, accA);
        matmul(ownB, othaB, othbB, othcB, qnB, accB);
        prx(zA, cQA, accA, ownA);
        prx(zB, cQB, accB, ownB);
        exchange(0);
    }
    {   // final differentiable step: cf = prox(c15 - mu*(c15@X - q))
        matmul(ownA, othaA, othbA, othcA, qnA, accA);
        matmul(ownB, othaB, othbB, othcB, qnB, accB);
        prx(cQA, cQA, accA, ownA);
        prx(cQB, cQB, accB, ownB);
        exchange(1);
    }
    if (write_cf) {                             // persist full cf (own slot per wave)
        u32x4* cpA = (u32x4*)(cfgb + ((size_t)(2 * blk) * 64 + lane) * 16);
        u32x4* cpB = (u32x4*)(cfgb + ((size_t)(2 * blk + 1) * 64 + lane) * 16);
        cpA[w] = ownA;
        cpB[w] = ownB;
    }

    // ---- pred (j-major; jm 0-2|3-4|5-6|7-8 across waves, ANTBP shared) ----
    {
        float pmA = pm[pA], pmB = pm[pB];
        f32x4 pmA4 = (f32x4){pmA, pmA, pmA, pmA};
        f32x4 pmB4 = (f32x4){pmB, pmB, pmB, pmB};
        int jm0 = (w == 0) ? 0 : (2 * w + 1);
        int jmN = (w == 0) ? 3 : 2;
        #pragma unroll
        for (int ji = 0; ji < 3; ++ji) {
            if (ji < jmN) {
                int jm = jm0 + ji;
                const unsigned short* Ar = &ANTBP[(jm * 16 + col) * 128 + 8 * Q];
                short8_t an_o = *(const short8_t*)&Ar[32 * w];
                short8_t an_a = *(const short8_t*)&Ar[32 * sa];
                short8_t an_b = *(const short8_t*)&Ar[32 * sb];
                short8_t an_c = *(const short8_t*)&Ar[32 * sc];
                f32x4 a = pmA4;
                a = __builtin_amdgcn_mfma_f32_16x16x32_bf16(an_o,
                        __builtin_bit_cast(short8_t, ownA), a, 0, 0, 0);
                a = __builtin_amdgcn_mfma_f32_16x16x32_bf16(an_a,
                        __builtin_bit_cast(short8_t, othaA), a, 0, 0, 0);
                a = __builtin_amdgcn_mfma_f32_16x16x32_bf16(an_b,
                        __builtin_bit_cast(short8_t, othbA), a, 0, 0, 0);
                a = __builtin_amdgcn_mfma_f32_16x16x32_bf16(an_c,
                        __builtin_bit_cast(short8_t, othcA), a, 0, 0, 0);
                f32x4 bb = pmB4;
                bb = __builtin_amdgcn_mfma_f32_16x16x32_bf16(an_o,
                         __builtin_bit_cast(short8_t, ownB), bb, 0, 0, 0);
                bb = __builtin_amdgcn_mfma_f32_16x16x32_bf16(an_a,
                         __builtin_bit_cast(short8_t, othaB), bb, 0, 0, 0);
                bb = __builtin_amdgcn_mfma_f32_16x16x32_bf16(an_b,
                         __builtin_bit_cast(short8_t, othbB), bb, 0, 0, 0);
                bb = __builtin_amdgcn_mfma_f32_16x16x32_bf16(an_c,
                         __builtin_bit_cast(short8_t, othcB), bb, 0, 0, 0);
                #pragma unroll
                for (int r = 0; r < 4; ++r) {
                    predh[(jm * 16 + 4 * Q + r) * 32768 + pA] = f2bh(a[r]);
                    predh[(jm * 16 + 4 * Q + r) * 32768 + pB] = f2bh(bb[r]);
                }
            }
        }
    }
}

// ---- fold via LDS staging: block = (output row i, batch b); j-major bf16 pred. ----
__global__ __launch_bounds__(256) void k_fold(const float* y, const float* beta_p,
                                              const unsigned short* predh, float* goal,
                                              float* out, int write_out) {
    __shared__ float P[12 * 832];              // 39,936 B
    int i = blockIdx.x, b = blockIdx.y;
    int t = threadIdx.x;
    for (int di = 0; di < 12; ++di) {
        int pi = i - di;
        if ((unsigned)pi >= 64u) continue;     // uniform per block
        int base = (b << 12) + (pi << 6);
        #pragma unroll
        for (int it = 0; it < 3; ++it) {
            int e = t + it * 256;              // < 768 = 12 dj * 64 pj
            int dj = e >> 6, pj = e & 63;      // consecutive t -> consecutive pj
            P[di * 832 + pj * 13 + dj] = bf2f(predh[(di * 12 + dj) * 32768 + base + pj]);
        }
    }
    __syncthreads();
    if (t >= 75) return;
    int j = t;
    float S = 0.f;
    for (int di = 0; di < 12; ++di) {
        if ((unsigned)(i - di) >= 64u) continue;
        const float* Pd = &P[di * 832];
        #pragma unroll
        for (int dj = 0; dj < 12; ++dj) {
            int pj = j - dj;
            if ((unsigned)pj >= 64u) continue;
            S += Pd[pj * 13 + dj];
        }
    }
    int ci = min(i, 11) - max(i - 63, 0) + 1;
    int cj = min(j, 11) - max(j - 63, 0) + 1;
    float beta = fmaxf(beta_p[0], 0.0f);
    int idx = i * 75 + j;
    float yv = y[b * 5625 + idx];
    float g = (yv + beta * S) / (1.0f + beta * (float)(ci * cj));
    if (write_out) out[b * 5625 + idx] = g;
    else           goal[b * 5625 + idx] = g;
}

extern "C" void kernel_launch(void* const* d_in, const int* in_sizes, int n_in,
                              void* d_out, int out_size, void* d_ws, size_t ws_size,
                              hipStream_t stream) {
    const float* y     = (const float*)d_in[0];
    const float* atoms = (const float*)d_in[1];
    const float* beta  = (const float*)d_in[2];
    const float* mu    = (const float*)d_in[3];
    float* out = (float*)d_out;
    float* ws = (float*)d_ws;

    k_setup<<<46, 1024, 0, stream>>>(atoms, mu, ws, y);   // block0 chain + workers goal/pm
    k_finalize<<<216, 256, 0, stream>>>(ws);              // XPB + ATB + ANTBP

    for (int u = 0; u < 2; ++u) {
        k_fista<<<1024, 256, 0, stream>>>((const unsigned short*)(ws + OFS_X),
                                          ws + OFS_GOAL,
                                          (const unsigned short*)(ws + OFS_ATB),
                                          (const unsigned short*)(ws + OFS_ANTB),
                                          ws + OFS_PM, (uint32_t*)(ws + OFS_CF),
                                          (unsigned short*)(ws + OFS_PRED),
                                          u == 0 ? 1 : 0, u == 0 ? 1 : 0);
        k_fold<<<dim3(75, 8), 256, 0, stream>>>(y, beta,
                                                (const unsigned short*)(ws + OFS_PRED),
                                                ws + OFS_GOAL, out, u == 1 ? 1 : 0);
    }
}